// Round 1
// baseline (1475.908 us; speedup 1.0000x reference)
//
#include <hip/hip_runtime.h>

// Problem constants
#define B_   4
#define S_   1024
#define D_   1024
#define H_   16
#define HD_  64
#define TD_  3072   // 3*D

// ---------------------------------------------------------------------------
// Generic fp32 tiled GEMM: C[64x64 tile] = A[M,K] @ B[K,N] (+ bias)
// A row-major stride lda, B row-major stride ldb, C row-major stride ldc.
// Per-z offsets decompose z = zo*16 + zi:  ptr += zo*Zo + zi*Zi.
// Grid: (N/64, M/64, Z). Block: 256 threads (16x16, 4x4 micro-tile).
// Requires K % 16 == 0, all tiles full (no bounds checks).
// ---------------------------------------------------------------------------
__global__ __launch_bounds__(256) void gemm64(
    const float* __restrict__ A, int lda, long long aZo, long long aZi,
    const float* __restrict__ B, int ldb, long long bZo, long long bZi,
    float* __restrict__ C, int ldc, long long cZo, long long cZi,
    const float* __restrict__ bias, int K)
{
    const int z  = blockIdx.z;
    const int zo = z >> 4, zi = z & 15;
    A += (long long)zo * aZo + (long long)zi * aZi;
    B += (long long)zo * bZo + (long long)zi * bZi;
    C += (long long)zo * cZo + (long long)zi * cZi;

    __shared__ float As[16][68];   // [kk][m], pad->2-way max (free)
    __shared__ float Bs[16][68];   // [kk][n]

    const int tid = threadIdx.x;
    const int tx = tid & 15;        // 0..15  (N direction)
    const int ty = tid >> 4;        // 0..15  (M direction)
    const int bm = blockIdx.y * 64;
    const int bn = blockIdx.x * 64;

    // A-load mapping: 64 rows x 16 k -> float4 per thread
    const int arow = tid >> 2;            // 0..63
    const int akk  = (tid & 3) << 2;      // 0,4,8,12
    // B-load mapping: 16 k-rows x 64 cols -> float4 per thread
    const int bkk  = tid >> 4;            // 0..15
    const int bc   = (tid & 15) << 2;     // 0..60

    float acc[4][4] = {};

    for (int k0 = 0; k0 < K; k0 += 16) {
        float4 a4 = *(const float4*)(A + (long long)(bm + arow) * lda + k0 + akk);
        float4 b4 = *(const float4*)(B + (long long)(k0 + bkk) * ldb + bn + bc);
        // transpose-store A
        As[akk + 0][arow] = a4.x;
        As[akk + 1][arow] = a4.y;
        As[akk + 2][arow] = a4.z;
        As[akk + 3][arow] = a4.w;
        *(float4*)&Bs[bkk][bc] = b4;
        __syncthreads();
#pragma unroll
        for (int kk = 0; kk < 16; ++kk) {
            float4 a = *(const float4*)&As[kk][ty << 2];
            float4 b = *(const float4*)&Bs[kk][tx << 2];
            float av[4] = {a.x, a.y, a.z, a.w};
            float bv[4] = {b.x, b.y, b.z, b.w};
#pragma unroll
            for (int i = 0; i < 4; ++i)
#pragma unroll
                for (int j = 0; j < 4; ++j)
                    acc[i][j] += av[i] * bv[j];
        }
        __syncthreads();
    }

    // epilogue
#pragma unroll
    for (int i = 0; i < 4; ++i) {
        float4 v = {acc[i][0], acc[i][1], acc[i][2], acc[i][3]};
        if (bias) {
            const float* bp = bias + bn + (tx << 2);
            v.x += bp[0]; v.y += bp[1]; v.z += bp[2]; v.w += bp[3];
        }
        *(float4*)(C + (long long)(bm + (ty << 2) + i) * ldc + bn + (tx << 2)) = v;
    }
}

// ---------------------------------------------------------------------------
// Attention logits + softmax.
// qkv layout: [B*S, 3072]; head h cols: q=[h*192, +64), k=[h*192+64, +64),
// v=[h*192+128, +64).
// One block = 16 Q-rows of one (b,h). Grid: (S/16, B*H). 256 threads = 4 waves,
// wave w handles rows w*4..w*4+3; lane handles key (t*64 + lane), t=0..15.
// Logits buffered in LDS (64KB); exact softmax (max-subtract).
// attn output: [B,H,S,S] at attn base.
// ---------------------------------------------------------------------------
__global__ __launch_bounds__(256) void attn_softmax(
    const float* __restrict__ qkv, float* __restrict__ attn)
{
    const int qb   = blockIdx.x;       // 0..63 (q-row block)
    const int bh   = blockIdx.y;       // 0..63
    const int b    = bh >> 4;
    const int h    = bh & 15;
    const int tid  = threadIdx.x;
    const int lane = tid & 63;
    const int wv   = tid >> 6;         // 0..3
    const int r0   = wv << 2;          // first of 4 rows for this wave

    __shared__ float Qs[16][64];
    __shared__ float Ls[16][1024];     // logits / exp buffer (64KB)

    // stage Q tile: 16 rows x 64 floats, one float4 per thread
    {
        const int r  = tid >> 4;
        const int d4 = (tid & 15) << 2;
        const float* qp = qkv + ((long long)(b * S_ + qb * 16 + r) * TD_ + h * 192 + d4);
        *(float4*)&Qs[r][d4] = *(const float4*)qp;
    }
    __syncthreads();

    const float* kbase = qkv + ((long long)b * S_ * TD_ + h * 192 + 64);
    const float scale = 0.125f;   // 1/sqrt(64)

    float m0 = -1e30f, m1 = -1e30f, m2 = -1e30f, m3 = -1e30f;

    for (int t = 0; t < 16; ++t) {
        const int key = (t << 6) + lane;
        const float* kp = kbase + (long long)key * TD_;
        float a0 = 0.f, a1 = 0.f, a2 = 0.f, a3 = 0.f;
#pragma unroll
        for (int d = 0; d < 64; d += 4) {
            float4 k4 = *(const float4*)(kp + d);
            float4 q;
            q = *(const float4*)&Qs[r0 + 0][d];
            a0 += q.x * k4.x + q.y * k4.y + q.z * k4.z + q.w * k4.w;
            q = *(const float4*)&Qs[r0 + 1][d];
            a1 += q.x * k4.x + q.y * k4.y + q.z * k4.z + q.w * k4.w;
            q = *(const float4*)&Qs[r0 + 2][d];
            a2 += q.x * k4.x + q.y * k4.y + q.z * k4.z + q.w * k4.w;
            q = *(const float4*)&Qs[r0 + 3][d];
            a3 += q.x * k4.x + q.y * k4.y + q.z * k4.z + q.w * k4.w;
        }
        a0 *= scale; a1 *= scale; a2 *= scale; a3 *= scale;
        Ls[r0 + 0][key] = a0;  m0 = fmaxf(m0, a0);
        Ls[r0 + 1][key] = a1;  m1 = fmaxf(m1, a1);
        Ls[r0 + 2][key] = a2;  m2 = fmaxf(m2, a2);
        Ls[r0 + 3][key] = a3;  m3 = fmaxf(m3, a3);
    }

    // wave-wide max reduction (width 64)
#pragma unroll
    for (int off = 32; off > 0; off >>= 1) {
        m0 = fmaxf(m0, __shfl_xor(m0, off, 64));
        m1 = fmaxf(m1, __shfl_xor(m1, off, 64));
        m2 = fmaxf(m2, __shfl_xor(m2, off, 64));
        m3 = fmaxf(m3, __shfl_xor(m3, off, 64));
    }

    // exp + sum
    float s0 = 0.f, s1 = 0.f, s2 = 0.f, s3 = 0.f;
    for (int t = 0; t < 16; ++t) {
        const int key = (t << 6) + lane;
        float e0 = __expf(Ls[r0 + 0][key] - m0);
        float e1 = __expf(Ls[r0 + 1][key] - m1);
        float e2 = __expf(Ls[r0 + 2][key] - m2);
        float e3 = __expf(Ls[r0 + 3][key] - m3);
        Ls[r0 + 0][key] = e0;  s0 += e0;
        Ls[r0 + 1][key] = e1;  s1 += e1;
        Ls[r0 + 2][key] = e2;  s2 += e2;
        Ls[r0 + 3][key] = e3;  s3 += e3;
    }
#pragma unroll
    for (int off = 32; off > 0; off >>= 1) {
        s0 += __shfl_xor(s0, off, 64);
        s1 += __shfl_xor(s1, off, 64);
        s2 += __shfl_xor(s2, off, 64);
        s3 += __shfl_xor(s3, off, 64);
    }
    const float i0 = 1.f / s0, i1 = 1.f / s1, i2 = 1.f / s2, i3 = 1.f / s3;

    // normalized write, coalesced along keys
    float* out = attn + ((long long)bh * S_ + qb * 16) * S_;
    for (int t = 0; t < 16; ++t) {
        const int key = (t << 6) + lane;
        out[(long long)(r0 + 0) * S_ + key] = Ls[r0 + 0][key] * i0;
        out[(long long)(r0 + 1) * S_ + key] = Ls[r0 + 1][key] * i1;
        out[(long long)(r0 + 2) * S_ + key] = Ls[r0 + 2][key] * i2;
        out[(long long)(r0 + 3) * S_ + key] = Ls[r0 + 3][key] * i3;
    }
}

// ---------------------------------------------------------------------------
extern "C" void kernel_launch(void* const* d_in, const int* in_sizes, int n_in,
                              void* d_out, int out_size, void* d_ws, size_t ws_size,
                              hipStream_t stream)
{
    const float* x     = (const float*)d_in[0];   // [4,1024,1024]
    const float* W_qkv = (const float*)d_in[1];   // [1024,3072]
    const float* b_qkv = (const float*)d_in[2];   // [3072]
    const float* W_o   = (const float*)d_in[3];   // [1024,1024]
    const float* b_o   = (const float*)d_in[4];   // [1024]

    float* o_out    = (float*)d_out;                         // [4,1024,1024]
    float* attn_out = o_out + (long long)B_ * S_ * D_;       // [4,16,1024,1024]

    float* qkv_ws    = (float*)d_ws;                          // [4096,3072]
    float* values_ws = qkv_ws + (long long)B_ * S_ * TD_;     // [4096,1024]

    // 1) qkv = x @ W_qkv + b_qkv     [4096,1024]@[1024,3072]
    gemm64<<<dim3(TD_ / 64, (B_ * S_) / 64, 1), 256, 0, stream>>>(
        x, D_, 0, 0,
        W_qkv, TD_, 0, 0,
        qkv_ws, TD_, 0, 0,
        b_qkv, D_);

    // 2) attention = softmax(q k^T / 8)   -> attn_out [B,H,S,S]
    attn_softmax<<<dim3(S_ / 16, B_ * H_), 256, 0, stream>>>(qkv_ws, attn_out);

    // 3) values = attention @ v  (per b,h)  -> values_ws [B,S,H*hd]
    //    z = b*16 + h
    gemm64<<<dim3(1, S_ / 64, B_ * H_), 256, 0, stream>>>(
        attn_out, S_, (long long)16 * S_ * S_, (long long)S_ * S_,
        qkv_ws + 128, TD_, (long long)S_ * TD_, 192,
        values_ws, D_, (long long)S_ * D_, HD_,
        nullptr, S_);

    // 4) o = values @ W_o + b_o     [4096,1024]@[1024,1024]
    gemm64<<<dim3(D_ / 64, (B_ * S_) / 64, 1), 256, 0, stream>>>(
        values_ws, D_, 0, 0,
        W_o, D_, 0, 0,
        o_out, D_, 0, 0,
        b_o, D_);
}

// Round 2
// 475.102 us; speedup vs baseline: 3.1065x; 3.1065x over previous
//
#include <hip/hip_runtime.h>

#define B_   4
#define S_   1024
#define D_   1024
#define H_   16
#define HD_  64

typedef __bf16 bf16_t;
typedef __attribute__((ext_vector_type(8))) __bf16 bf16x8;
typedef __attribute__((ext_vector_type(4))) float f32x4;

#define MFMA16(a, b, c) __builtin_amdgcn_mfma_f32_16x16x32_bf16((a), (b), (c), 0, 0, 0)

__device__ inline unsigned short f2bf(float f) {
    unsigned int u = __builtin_bit_cast(unsigned int, f);
    u += 0x7FFFu + ((u >> 16) & 1u);   // RNE
    return (unsigned short)(u >> 16);
}

__device__ inline bf16x8 ld_frag(const unsigned short* p) {
    uint4 u = *(const uint4*)p;
    return __builtin_bit_cast(bf16x8, u);
}

// ---------------------------------------------------------------------------
// Elementwise fp32 -> bf16 (x). One float4 per thread.
// ---------------------------------------------------------------------------
__global__ __launch_bounds__(256) void convert_f32_bf16(
    const float* __restrict__ in, unsigned short* __restrict__ out)
{
    const size_t idx = (size_t)blockIdx.x * 256 + threadIdx.x;
    float4 v = *(const float4*)(in + idx * 4);
    unsigned short* o = out + idx * 4;
    ushort4 r;
    r.x = f2bf(v.x); r.y = f2bf(v.y); r.z = f2bf(v.z); r.w = f2bf(v.w);
    *(ushort4*)o = r;
}

// ---------------------------------------------------------------------------
// Transpose + convert: in fp32 [K][N] -> out bf16 [N][K]. 64x64 tiles.
// Grid: (N/64, K/64), 256 threads.
// ---------------------------------------------------------------------------
__global__ __launch_bounds__(256) void transpose_f32_bf16(
    const float* __restrict__ in, unsigned short* __restrict__ out,
    int K, int N)
{
    __shared__ float T[64][65];
    const int tid = threadIdx.x;
    const int k0 = blockIdx.y * 64, n0 = blockIdx.x * 64;
#pragma unroll
    for (int i = 0; i < 4; ++i) {
        int c = tid + i * 256;              // 1024 float4 chunks
        int row = c >> 4, col = (c & 15) << 2;
        float4 v = *(const float4*)(in + (size_t)(k0 + row) * N + n0 + col);
        T[row][col + 0] = v.x; T[row][col + 1] = v.y;
        T[row][col + 2] = v.z; T[row][col + 3] = v.w;
    }
    __syncthreads();
#pragma unroll
    for (int i = 0; i < 4; ++i) {
        int c = tid + i * 256;
        int nr = c >> 4, kc = (c & 15) << 2;
        ushort4 r;
        r.x = f2bf(T[kc + 0][nr]); r.y = f2bf(T[kc + 1][nr]);
        r.z = f2bf(T[kc + 2][nr]); r.w = f2bf(T[kc + 3][nr]);
        *(ushort4*)(out + (size_t)(n0 + nr) * K + k0 + kc) = r;
    }
}

// ---------------------------------------------------------------------------
// bf16 MFMA GEMM: C[M,N] = A[M,K] @ Bt[N,K]^T + bias.
// 128x128 tile, 256 threads = 4 waves (2x2), each wave 64x64 (4x4 MFMA tiles).
// MODE 0 (QKV): write q,k -> qk[row][head*128 + 0..127] (bf16),
//               v -> vt[(b*16+head)][dim][key] (bf16, transposed).
// MODE 1: fp32 out[M][N].
// ---------------------------------------------------------------------------
template<int MODE>
__global__ __launch_bounds__(256) void gemm_bf16(
    const unsigned short* __restrict__ A,
    const unsigned short* __restrict__ Bt,
    const float* __restrict__ bias,
    unsigned short* __restrict__ qk,
    unsigned short* __restrict__ vt,
    float* __restrict__ out,
    int K, int N)
{
    __shared__ unsigned short Alds[128][72];
    __shared__ unsigned short Blds[128][72];
    const int tid  = threadIdx.x;
    const int l    = tid & 63, w = tid >> 6;
    const int wm   = w >> 1, wn = w & 1;
    const int quad = l >> 4, n16 = l & 15;
    const int bm = blockIdx.y * 128, bn = blockIdx.x * 128;

    const f32x4 zero4 = {0.f, 0.f, 0.f, 0.f};
    f32x4 acc[4][4];
#pragma unroll
    for (int i = 0; i < 4; ++i)
#pragma unroll
        for (int j = 0; j < 4; ++j) acc[i][j] = zero4;

    for (int k0 = 0; k0 < K; k0 += 64) {
#pragma unroll
        for (int i = 0; i < 4; ++i) {
            int c = tid + i * 256;
            int row = c >> 3, off = (c & 7) << 3;
            *(uint4*)&Alds[row][off] = *(const uint4*)(A + (size_t)(bm + row) * K + k0 + off);
            *(uint4*)&Blds[row][off] = *(const uint4*)(Bt + (size_t)(bn + row) * K + k0 + off);
        }
        __syncthreads();
#pragma unroll
        for (int kk = 0; kk < 2; ++kk) {
            const int kc = kk * 32 + quad * 8;
            bf16x8 af[4], bfv[4];
#pragma unroll
            for (int i = 0; i < 4; ++i) af[i]  = ld_frag(&Alds[wm * 64 + i * 16 + n16][kc]);
#pragma unroll
            for (int j = 0; j < 4; ++j) bfv[j] = ld_frag(&Blds[wn * 64 + j * 16 + n16][kc]);
#pragma unroll
            for (int i = 0; i < 4; ++i)
#pragma unroll
                for (int j = 0; j < 4; ++j)
                    acc[i][j] = MFMA16(af[i], bfv[j], acc[i][j]);
        }
        __syncthreads();
    }

    // epilogue
#pragma unroll
    for (int j = 0; j < 4; ++j) {
        const int col0 = bn + wn * 64 + j * 16;
        const int col  = col0 + n16;
        const float bv = bias ? bias[col] : 0.f;
        if (MODE == 0) {
            const int head = col0 / 192;
            const int rem  = col0 % 192;
            if (rem < 128) {
#pragma unroll
                for (int i = 0; i < 4; ++i)
#pragma unroll
                    for (int r = 0; r < 4; ++r) {
                        int row = bm + wm * 64 + i * 16 + quad * 4 + r;
                        qk[(size_t)row * 2048 + head * 128 + rem + n16] =
                            f2bf(acc[i][j][r] + bv);
                    }
            } else {
                const int dim = rem - 128 + n16;
#pragma unroll
                for (int i = 0; i < 4; ++i)
#pragma unroll
                    for (int r = 0; r < 4; ++r) {
                        int row = bm + wm * 64 + i * 16 + quad * 4 + r;
                        vt[(size_t)(((row >> 10) << 4) + head) * 65536 +
                           (size_t)dim * 1024 + (row & 1023)] =
                            f2bf(acc[i][j][r] + bv);
                    }
            }
        } else {
#pragma unroll
            for (int i = 0; i < 4; ++i)
#pragma unroll
                for (int r = 0; r < 4; ++r) {
                    int row = bm + wm * 64 + i * 16 + quad * 4 + r;
                    out[(size_t)row * N + col] = acc[i][j][r] + bv;
                }
        }
    }
}

// ---------------------------------------------------------------------------
// Fused attention: per block = 16 Q-rows of one (b,h).
// Phase 1: QK^T via MFMA (logits in 16 C-frags = all 1024 keys / wave-chunked),
// Phase 2: register softmax (cross-wave combine via tiny LDS),
//          write attention fp32, P -> LDS bf16,
// Phase 3: AV via MFMA (V from vt[bh][dim][key], coalesced stage).
// Grid (S/16, B*H), 256 threads = 4 waves.
// ---------------------------------------------------------------------------
__global__ __launch_bounds__(256) void attn_fused(
    const unsigned short* __restrict__ qk,   // [4096][2048]
    const unsigned short* __restrict__ vt,   // [64][64][1024]
    float* __restrict__ attn,                // [64][1024][1024]
    unsigned short* __restrict__ values)     // [4096][1024]
{
    __shared__ unsigned short Klds[64][72];
    __shared__ unsigned short Vlds[64][72];
    __shared__ unsigned short Plds[16][1032];
    __shared__ float redbuf[2][4][16];

    const int qb = blockIdx.x, bh = blockIdx.y;
    const int b = bh >> 4, h = bh & 15;
    const int tid = threadIdx.x, l = tid & 63, w = tid >> 6;
    const int quad = l >> 4, n16 = l & 15;

    // preload Q A-frags (held all kernel): Q[m=n16][k], k-steps 0,1
    bf16x8 qf[2];
    {
        const unsigned short* qbase =
            qk + (size_t)(b * 1024 + qb * 16 + n16) * 2048 + h * 128 + quad * 8;
        qf[0] = ld_frag(qbase);
        qf[1] = ld_frag(qbase + 32);
    }

    const f32x4 zero4 = {0.f, 0.f, 0.f, 0.f};
    f32x4 c[16];
#pragma unroll
    for (int s = 0; s < 16; ++s) c[s] = zero4;

    // ---- Phase 1: QK^T ----
    const unsigned short* kbase = qk + (size_t)(b * 1024) * 2048 + h * 128 + 64;
    for (int s = 0; s < 16; ++s) {
#pragma unroll
        for (int i = 0; i < 2; ++i) {
            int cc = tid + i * 256;
            int key = cc >> 3, off = (cc & 7) << 3;
            *(uint4*)&Klds[key][off] =
                *(const uint4*)(kbase + (size_t)(s * 64 + key) * 2048 + off);
        }
        __syncthreads();
        const int krow = w * 16 + n16;
        bf16x8 k0f = ld_frag(&Klds[krow][quad * 8]);
        bf16x8 k1f = ld_frag(&Klds[krow][32 + quad * 8]);
        c[s] = MFMA16(qf[0], k0f, c[s]);
        c[s] = MFMA16(qf[1], k1f, c[s]);
        __syncthreads();
    }

    // ---- Phase 2: softmax in registers ----
    float mx[4] = {-1e30f, -1e30f, -1e30f, -1e30f};
#pragma unroll
    for (int s = 0; s < 16; ++s)
#pragma unroll
        for (int r = 0; r < 4; ++r) {
            c[s][r] *= 0.125f;                  // 1/sqrt(64)
            mx[r] = fmaxf(mx[r], c[s][r]);
        }
#pragma unroll
    for (int off = 1; off <= 8; off <<= 1)
#pragma unroll
        for (int r = 0; r < 4; ++r)
            mx[r] = fmaxf(mx[r], __shfl_xor(mx[r], off, 64));
    if (n16 == 0)
#pragma unroll
        for (int r = 0; r < 4; ++r) redbuf[0][w][quad * 4 + r] = mx[r];
    __syncthreads();
#pragma unroll
    for (int r = 0; r < 4; ++r) {
        const int row = quad * 4 + r;
        float m = redbuf[0][0][row];
        m = fmaxf(m, redbuf[0][1][row]);
        m = fmaxf(m, redbuf[0][2][row]);
        m = fmaxf(m, redbuf[0][3][row]);
        mx[r] = m;
    }

    float sm[4] = {0.f, 0.f, 0.f, 0.f};
#pragma unroll
    for (int s = 0; s < 16; ++s)
#pragma unroll
        for (int r = 0; r < 4; ++r) {
            float e = __expf(c[s][r] - mx[r]);
            c[s][r] = e;
            sm[r] += e;
        }
#pragma unroll
    for (int off = 1; off <= 8; off <<= 1)
#pragma unroll
        for (int r = 0; r < 4; ++r)
            sm[r] += __shfl_xor(sm[r], off, 64);
    if (n16 == 0)
#pragma unroll
        for (int r = 0; r < 4; ++r) redbuf[1][w][quad * 4 + r] = sm[r];
    __syncthreads();
    float inv[4];
#pragma unroll
    for (int r = 0; r < 4; ++r) {
        const int row = quad * 4 + r;
        inv[r] = 1.f / (redbuf[1][0][row] + redbuf[1][1][row] +
                        redbuf[1][2][row] + redbuf[1][3][row]);
    }

    // write attention (fp32) + P (bf16 to LDS for AV)
    float* abase = attn + ((size_t)bh * 1024 + qb * 16) * 1024;
#pragma unroll
    for (int s = 0; s < 16; ++s)
#pragma unroll
        for (int r = 0; r < 4; ++r) {
            const float a = c[s][r] * inv[r];
            const int row = quad * 4 + r;
            const int key = s * 64 + w * 16 + n16;
            abase[(size_t)row * 1024 + key] = a;
            Plds[row][key] = f2bf(a);
        }

    // ---- Phase 3: AV ----
    f32x4 o = zero4;
    const unsigned short* vbase = vt + (size_t)bh * 65536;
    for (int s = 0; s < 16; ++s) {
#pragma unroll
        for (int i = 0; i < 2; ++i) {
            int cc = tid + i * 256;
            int dim = cc >> 3, off = (cc & 7) << 3;
            *(uint4*)&Vlds[dim][off] =
                *(const uint4*)(vbase + (size_t)dim * 1024 + s * 64 + off);
        }
        __syncthreads();
#pragma unroll
        for (int kk = 0; kk < 2; ++kk) {
            bf16x8 pf = ld_frag(&Plds[n16][s * 64 + kk * 32 + quad * 8]);
            bf16x8 vf = ld_frag(&Vlds[w * 16 + n16][kk * 32 + quad * 8]);
            o = MFMA16(pf, vf, o);
        }
        __syncthreads();
    }

#pragma unroll
    for (int r = 0; r < 4; ++r) {
        const int row = quad * 4 + r;
        values[(size_t)(b * 1024 + qb * 16 + row) * 1024 + h * 64 + w * 16 + n16] =
            f2bf(o[r]);
    }
}

// ---------------------------------------------------------------------------
extern "C" void kernel_launch(void* const* d_in, const int* in_sizes, int n_in,
                              void* d_out, int out_size, void* d_ws, size_t ws_size,
                              hipStream_t stream)
{
    const float* x     = (const float*)d_in[0];   // [4,1024,1024]
    const float* W_qkv = (const float*)d_in[1];   // [1024,3072]
    const float* b_qkv = (const float*)d_in[2];   // [3072]
    const float* W_o   = (const float*)d_in[3];   // [1024,1024]
    const float* b_o   = (const float*)d_in[4];   // [1024]

    float* o_out    = (float*)d_out;                          // [4096,1024] fp32
    float* attn_out = o_out + (size_t)B_ * S_ * D_;           // [64,1024,1024] fp32

    const size_t M1 = 1ull << 20;
    unsigned short* ws      = (unsigned short*)d_ws;
    unsigned short* x_bf    = ws;                 // 4M  [4096][1024]
    unsigned short* wqkvt   = ws + 4 * M1;        // 3M  [3072][1024]
    unsigned short* wot     = ws + 7 * M1;        // 1M  [1024][1024]
    unsigned short* qkbuf   = ws + 8 * M1;        // 8M  [4096][2048]
    unsigned short* vtbuf   = ws + 16 * M1;       // 4M  [64][64][1024]
    unsigned short* valbuf  = ws + 20 * M1;       // 4M  [4096][1024]

    convert_f32_bf16<<<4096, 256, 0, stream>>>(x, x_bf);
    transpose_f32_bf16<<<dim3(3072 / 64, 1024 / 64), 256, 0, stream>>>(W_qkv, wqkvt, 1024, 3072);
    transpose_f32_bf16<<<dim3(1024 / 64, 1024 / 64), 256, 0, stream>>>(W_o, wot, 1024, 1024);

    gemm_bf16<0><<<dim3(3072 / 128, 4096 / 128), 256, 0, stream>>>(
        x_bf, wqkvt, b_qkv, qkbuf, vtbuf, nullptr, 1024, 3072);

    attn_fused<<<dim3(S_ / 16, B_ * H_), 256, 0, stream>>>(
        qkbuf, vtbuf, attn_out, valbuf);

    gemm_bf16<1><<<dim3(1024 / 128, 4096 / 128), 256, 0, stream>>>(
        valbuf, wot, b_o, nullptr, nullptr, o_out, 1024, 1024);
}